// Round 4
// baseline (13187.822 us; speedup 1.0000x reference)
//
#include <hip/hip_runtime.h>
#include <hip/hip_bf16.h>
#include <stdint.h>

typedef __hip_bfloat16 bf16;

// Shapes (N=1): S=128, R=256, CM=256, CZ=128, C=32, MSA_H=8, PAIR_H=4, CTM=128, FF=4
// msa rows: s*256+r (32768 x 256); pair rows: i*256+j (65536 x 128)
// I/O dtype: FLOAT32 (established round 3: JSON absmax 454 == max|pair_ref| with bf16 writes
//            => harness reads d_out as f32; round-1 NaN => inputs are f32).
// Accumulators: f32, living directly in d_out (msaF, pairF) — they ARE the outputs.
// Workspace (54 MB): weights 4MB | biasF 2MB | lnb 16MB | bufA 16MB | bufB 16MB (bf16 intermediates).

__device__ __forceinline__ float toF(float x){ return x; }
__device__ __forceinline__ float toF(bf16 x){ return __bfloat162float(x); }
__device__ __forceinline__ bf16  toB(float x){ return __float2bfloat16(x); }

// ---------------- input staging (dtype probe: bf16 ones -> 0x3F803F80, f32 one -> 0x3F800000) ----------------
__global__ void cvt_w_k(const void* __restrict__ in, bf16* __restrict__ out, int n,
                        const uint32_t* __restrict__ probe){
    bool isbf = (probe[0] == 0x3F803F80u);
    int i = blockIdx.x*256 + threadIdx.x;
    if (i < n) out[i] = isbf ? ((const bf16*)in)[i] : toB(((const float*)in)[i]);
}
__global__ void in2f_k(const void* __restrict__ in, float* __restrict__ out, int n,
                       const uint32_t* __restrict__ probe){
    bool isbf = (probe[0] == 0x3F803F80u);
    int i = blockIdx.x*256 + threadIdx.x;
    if (i < n) out[i] = isbf ? toF(((const bf16*)in)[i]) : ((const float*)in)[i];
}

// ---------------- LayerNorm: one block per row, blockDim = D (128 or 256) ----------------
template<typename T>
__global__ void ln_k(const T* __restrict__ x, const bf16* __restrict__ w, const bf16* __restrict__ b,
                     bf16* __restrict__ out, int D){
    int row = blockIdx.x, c = threadIdx.x;
    float v = toF(x[(size_t)row*D + c]);
    float s1 = v, s2 = v*v;
    #pragma unroll
    for (int o=32;o>0;o>>=1){ s1 += __shfl_down(s1,o); s2 += __shfl_down(s2,o); }
    __shared__ float r1[4], r2[4];
    int lane = c & 63, wid = c >> 6;
    if (lane==0){ r1[wid]=s1; r2[wid]=s2; }
    __syncthreads();
    int nw = blockDim.x >> 6;
    float m=0.f, q=0.f;
    for (int i=0;i<nw;i++){ m+=r1[i]; q+=r2[i]; }
    m /= (float)D; q = q/(float)D - m*m;
    float inv = rsqrtf(q + 1e-5f);
    out[(size_t)row*D + c] = toB((v-m)*inv*toF(w[c]) + toF(b[c]));
}

// ---------------- fused LN + attention-bias projection (reads f32 pair acc) ----------------
// mode 0 (row attn, Hn=8): out[(h*256+i)*256+j] ; mode 1 (tas, Hn=4): out[(i*Hn+h)*256+j]
// mode 2 (tae, Hn=4): out[(j*Hn+h)*256+i].  Value = dot(LN(pair[i,j]), Wb[:,h]).
__global__ void ln_bias_k(const float* __restrict__ pairf, const bf16* __restrict__ w, const bf16* __restrict__ b,
                          const bf16* __restrict__ Wb, float* __restrict__ outb, int Hn, int mode){
    int pp = blockIdx.x, c = threadIdx.x;           // 128 threads
    int i = pp >> 8, j = pp & 255;
    float v = pairf[(size_t)pp*128 + c];
    float s1 = v, s2 = v*v;
    #pragma unroll
    for (int o=32;o>0;o>>=1){ s1 += __shfl_down(s1,o); s2 += __shfl_down(s2,o); }
    __shared__ float r1[2], r2[2], rh[2];
    int lane = c & 63, wid = c >> 6;
    if (lane==0){ r1[wid]=s1; r2[wid]=s2; }
    __syncthreads();
    float m = (r1[0]+r1[1])*(1.f/128.f);
    float q = (r2[0]+r2[1])*(1.f/128.f) - m*m;
    float xn = (v-m)*rsqrtf(q+1e-5f)*toF(w[c]) + toF(b[c]);
    for (int h=0; h<Hn; ++h){
        float p = xn*toF(Wb[c*Hn + h]);
        #pragma unroll
        for (int o=32;o>0;o>>=1) p += __shfl_down(p,o);
        if (lane==0) rh[wid]=p;
        __syncthreads();
        if (c==0){
            float sv = rh[0]+rh[1];
            size_t idx = (mode==0) ? ((size_t)(h*256+i)*256 + j)
                       : (mode==1) ? ((size_t)(i*Hn+h)*256 + j)
                                   : ((size_t)(j*Hn+h)*256 + i);
            outb[idx] = sv;
        }
        __syncthreads();
    }
}

// ---------------- generic tiled GEMM (bf16 in, fp32 math), B row-stride ldb ----------------
// ACT: 0 none, 1 sigmoid, 2 relu. MUL: x *= Mul[m (or transposed)]. RES: f32 Res[m+res_off] += x, else C=bf16.
template<int ACT, int MUL, int RES>
__global__ __launch_bounds__(256) void gemm_k(const bf16* __restrict__ A, const bf16* __restrict__ Bw,
                                              bf16* __restrict__ C, float* __restrict__ Res,
                                              const bf16* __restrict__ Mul,
                                              int M, int N, int K, int ldb, int res_off, int gtrans){
    __shared__ float As[64][33];
    __shared__ float Bs[32][65];
    int tid = threadIdx.x;
    int m0 = blockIdx.y*64, n0 = blockIdx.x*64;
    int tx = tid & 15, ty = tid >> 4;
    float acc[4][4] = {};
    for (int k0=0; k0<K; k0+=32){
        for (int i=tid; i<64*32; i+=256){
            int r = i>>5, cc = i&31;
            As[r][cc] = toF(A[(size_t)(m0+r)*K + k0 + cc]);
        }
        for (int i=tid; i<32*64; i+=256){
            int r = i>>6, cc = i&63; int col = n0+cc;
            Bs[r][cc] = (col < N) ? toF(Bw[(size_t)(k0+r)*ldb + col]) : 0.f;
        }
        __syncthreads();
        #pragma unroll 8
        for (int k=0;k<32;k++){
            float a4[4], b4[4];
            #pragma unroll
            for (int i=0;i<4;i++) a4[i] = As[ty*4+i][k];
            #pragma unroll
            for (int j=0;j<4;j++) b4[j] = Bs[k][tx*4+j];
            #pragma unroll
            for (int i=0;i<4;i++)
                #pragma unroll
                for (int j=0;j<4;j++) acc[i][j] += a4[i]*b4[j];
        }
        __syncthreads();
    }
    #pragma unroll
    for (int i=0;i<4;i++){
        int m = m0 + ty*4 + i;
        #pragma unroll
        for (int j=0;j<4;j++){
            int n = n0 + tx*4 + j;
            if (n >= N) continue;
            float x = acc[i][j];
            if (ACT==1) x = 1.f/(1.f + __expf(-x));
            else if (ACT==2) x = fmaxf(x, 0.f);
            if (MUL){
                int mr = gtrans ? (((m & 255) << 8) | (m >> 8)) : m;
                x *= toF(Mul[(size_t)mr*N + n]);
            }
            if (RES) Res[(size_t)(m + res_off)*N + n] += x;
            else     C[(size_t)m*N + n] = toB(x);
        }
    }
}

// ---------------- fused attention: on-the-fly V projection, in-place output over Q ----------------
// Block (h, o), 256 thr = 4 waves; wave owns query rows q = wid, wid+4, ...
// Positions: pos(l) = o*sO + l*sL; row stride GN=H*32; L = 64*J (compile-time).
// QO: Q in / att (ungated) out, in place. Kp: K buffer. X: LN'd input (rows CD wide).
// Wqkv: (CD x 3*H*32); V col = (2H+h)*32+c.
// BIAS: 0 none, 1 bias[(h*256+q)*256+k], 2 bias[(o*H+h)*256+k] — added POST-softmax per reference.
template<int BIAS, int J, int CD>
__global__ __launch_bounds__(256) void attn2_k(bf16* __restrict__ QO, const bf16* __restrict__ Kp,
                                               const bf16* __restrict__ X, const bf16* __restrict__ Wqkv,
                                               const float* __restrict__ bias,
                                               int H, int sO, int sL){
    constexpr int L = 64*J;
    extern __shared__ char sm[];
    const int o = blockIdx.y, h = blockIdx.x, tid = threadIdx.x;
    const int lane = tid & 63;
    const int wid = tid >> 6;
    const int GN = H*32, ldw = 3*H*32;
    bf16* wv = (bf16*)sm;            // CD*33
    bf16* Kt = wv + CD*33;           // L*34
    bf16* Vt = Kt + L*34;            // L*34
    bf16* xs = Vt + L*34;            // 16*CD
    for (int idx=tid; idx<CD*32; idx+=256){
        int k = idx>>5, c = idx&31;
        wv[k*33+c] = Wqkv[(size_t)k*ldw + (2*H + h)*32 + c];
    }
    for (int idx=tid; idx<L*32; idx+=256){
        int l = idx>>5, c = idx&31;
        Kt[l*34+c] = Kp[(size_t)(o*sO + l*sL)*GN + h*32 + c];
    }
    constexpr int CSH = (CD==256) ? 8 : 7;
    for (int l0=0; l0<L; l0+=16){
        __syncthreads();                       // protects xs reuse + (first iter) wv/Kt staging
        for (int idx=tid; idx<16*CD; idx+=256){
            int r = idx >> CSH, k = idx & (CD-1);
            xs[r*CD + k] = X[(size_t)(o*sO + (l0+r)*sL)*CD + k];
        }
        __syncthreads();
        for (int idx=tid; idx<512; idx+=256){  // 16 rows x 32 cols
            int r = idx>>5, c = idx&31;
            float a = 0.f;
            #pragma unroll 8
            for (int k=0;k<CD;k++) a += toF(xs[r*CD+k]) * toF(wv[k*33+c]);
            Vt[(l0+r)*34 + c] = toB(a);
        }
    }
    __syncthreads();                           // Vt/Kt now read-only
    float s[J];
    for (int q0 = wid; q0 < L; q0 += 4){
        size_t pq = (size_t)(o*sO + q0*sL);
        float qreg = (lane < 32) ? toF(QO[pq*GN + h*32 + lane]) : 0.f;
        float mx = -1e30f;
        #pragma unroll
        for (int j=0;j<J;j++){
            int k = j*64 + lane;
            float a = 0.f;
            #pragma unroll
            for (int c=0;c<32;c++) a += __shfl(qreg, c) * toF(Kt[k*34+c]);
            s[j] = a * 0.17677669529663687f;   // 1/sqrt(32)
            mx = fmaxf(mx, s[j]);
        }
        #pragma unroll
        for (int off=32;off;off>>=1) mx = fmaxf(mx, __shfl_xor(mx, off));
        float sum = 0.f;
        #pragma unroll
        for (int j=0;j<J;j++){ s[j] = __expf(s[j]-mx); sum += s[j]; }
        #pragma unroll
        for (int off=32;off;off>>=1) sum += __shfl_xor(sum, off);
        float inv = 1.f/sum;
        #pragma unroll
        for (int j=0;j<J;j++){
            int k = j*64 + lane;
            float p = s[j]*inv;
            if (BIAS==1)      p += bias[((size_t)(h*256 + q0))*256 + k];
            else if (BIAS==2) p += bias[((size_t)(o*H + h))*256 + k];
            s[j] = p;
        }
        int c = lane & 31;
        float acc = 0.f;
        #pragma unroll
        for (int j=0;j<J;j++){
            #pragma unroll
            for (int m=0;m<32;m++){
                int srcl = (lane & 32) | m;
                float p = __shfl(s[j], srcl);
                acc += p * toF(Vt[(j*64 + srcl)*34 + c]);
            }
        }
        acc += __shfl_xor(acc, 32);
        if (lane < 32) QO[pq*GN + h*32 + c] = toB(acc);   // in-place over Q
    }
}

// ---------------- elementwise: a *= sigmoid(g) ----------------
__global__ void mulsig_k(bf16* __restrict__ a, const bf16* __restrict__ g, int n){
    int i = blockIdx.x*256 + threadIdx.x;
    if (i < n){
        float sg = 1.f/(1.f + __expf(-toF(g[i])));
        a[i] = toB(toF(a[i]) * sg);
    }
}

// ---------------- triangle multiplication einsum ----------------
// outgoing: p[s,t,k] = sum_r a[s,r,k]*b[t,r,k]; incoming: p[s,t,k] = sum_r a[r,s,k]*b[r,t,k]
__global__ void trimul_k(const bf16* __restrict__ a, const bf16* __restrict__ b, bf16* __restrict__ p, int incoming){
    int t = blockIdx.x, s = blockIdx.y, k = threadIdx.x;   // 128 threads
    float acc = 0.f;
    if (!incoming){
        const bf16* pa = a + (size_t)(s*256)*128 + k;
        const bf16* pb = b + (size_t)(t*256)*128 + k;
        for (int r=0;r<256;r++) acc += toF(pa[(size_t)r*128]) * toF(pb[(size_t)r*128]);
    } else {
        const bf16* pa = a + (size_t)s*128 + k;
        const bf16* pb = b + (size_t)t*128 + k;
        for (int r=0;r<256;r++) acc += toF(pa[(size_t)r*32768]) * toF(pb[(size_t)r*32768]);
    }
    p[((size_t)s*256 + t)*128 + k] = toB(acc);
}

// ---------------- outer product einsum, chunked over r (32 r's per chunk) ----------------
// out[(rl*256+t)*1024 + c*32+e] = sum_s ap[(s*256+r)*32+c]*bp[(s*256+t)*32+e], r = r0+rl
__global__ __launch_bounds__(256) void outer_k(const bf16* __restrict__ ap, const bf16* __restrict__ bp,
                                               bf16* __restrict__ outc, int r0){
    int t = blockIdx.x, rl = blockIdx.y, r = r0 + rl;
    __shared__ float As[128*32], Bs[128*32];
    for (int idx=threadIdx.x; idx<128*32; idx+=256){
        int s = idx>>5, c = idx&31;
        As[idx] = toF(ap[((size_t)s*256 + r)*32 + c]);
        Bs[idx] = toF(bp[((size_t)s*256 + t)*32 + c]);
    }
    __syncthreads();
    int ce0 = threadIdx.x*4;
    int c = ce0 >> 5, e0 = ce0 & 31;
    float acc[4] = {0.f,0.f,0.f,0.f};
    for (int s=0;s<128;s++){
        float av = As[s*32 + c];
        #pragma unroll
        for (int j=0;j<4;j++) acc[j] += av*Bs[s*32 + e0 + j];
    }
    size_t row = (size_t)rl*256 + t;
    #pragma unroll
    for (int j=0;j<4;j++) outc[row*1024 + ce0 + j] = toB(acc[j]);
}

// ================= host =================
extern "C" void kernel_launch(void* const* d_in, const int* in_sizes, int n_in,
                              void* d_out, int out_size, void* d_ws, size_t ws_size,
                              hipStream_t stream){
    (void)n_in; (void)out_size; (void)ws_size;
    const int MSA_N  = 128*256*256;   // 8388608
    const int PAIR_N = 256*256*128;   // 8388608
    const uint32_t* probe = (const uint32_t*)d_in[2];   // row_norm_m_w = ones

    // ---- workspace layout: 54 MB total ----
    char*  w     = (char*)d_ws;
    bf16*  wsts  = (bf16*)(w);                 // [0, 4MB) staged bf16 weights
    float* biasF = (float*)(w + 4194304);      // [4MB, 6MB)
    bf16*  lnb   = (bf16*)(w + 6291456);       // [6MB, 22MB)
    bf16*  bufA  = (bf16*)(w + 23068672);      // [22MB, 38MB)
    bf16*  bufB  = (bf16*)(w + 39845888);      // [38MB, 54MB)

    float* msaF  = (float*)d_out;              // f32 msa accumulator == output 0
    float* pairF = msaF + MSA_N;               // f32 pair accumulator == output 1

    // ---- stage all weights (inputs 2..59) to bf16 ----
    size_t woff[64]; { size_t acc = 0;
        for (int i=2;i<60;i++){ woff[i] = acc; acc += ((size_t)in_sizes[i] + 63) & ~(size_t)63; } }
    #define W(i) (wsts + woff[i])
    for (int i=2;i<60;i++)
        cvt_w_k<<<(in_sizes[i]+255)/256,256,0,stream>>>(d_in[i], W(i), in_sizes[i], probe);

    // init f32 accumulators in d_out (inputs pristine each launch)
    in2f_k<<<32768,256,0,stream>>>(d_in[0], msaF,  MSA_N,  probe);
    in2f_k<<<32768,256,0,stream>>>(d_in[1], pairF, PAIR_N, probe);

    const size_t smem_row = (size_t)(256*33 + 2*256*34 + 16*256)*2;  // 59904
    const size_t smem_col = (size_t)(256*33 + 2*128*34 + 16*256)*2;  // 42496
    const size_t smem_tri = (size_t)(128*33 + 2*256*34 + 16*128)*2;  // 47360
    #define GEMM_GRID(M,N) dim3(((N)+63)/64, (M)/64)

    // ================= Row attention (bias from LN(pair)@row_bias, post-softmax) =================
    ln_k<float><<<32768,256,0,stream>>>(msaF, W(2), W(3), lnb, 256);
    ln_bias_k<<<65536,128,0,stream>>>(pairF, W(4), W(5), W(9), biasF, 8, 0);
    gemm_k<0,0,0><<<GEMM_GRID(32768,256),256,0,stream>>>(lnb, W(7),     bufA, nullptr, nullptr, 32768,256,256, 768, 0,0); // Q
    gemm_k<0,0,0><<<GEMM_GRID(32768,256),256,0,stream>>>(lnb, W(7)+256, bufB, nullptr, nullptr, 32768,256,256, 768, 0,0); // K
    attn2_k<1,4,256><<<dim3(8,128),256,smem_row,stream>>>(bufA, bufB, lnb, W(7), biasF, 8, 256, 1);
    gemm_k<0,0,0><<<GEMM_GRID(32768,256),256,0,stream>>>(lnb, W(6), bufB, nullptr, nullptr, 32768,256,256, 256, 0,0);     // gate raw
    mulsig_k<<<32768,256,0,stream>>>(bufA, bufB, MSA_N);
    gemm_k<0,0,1><<<GEMM_GRID(32768,256),256,0,stream>>>(bufA, W(8), nullptr, msaF, nullptr, 32768,256,256, 256, 0,0);

    // ================= Column attention (attend over s, L=128, no bias) =================
    ln_k<float><<<32768,256,0,stream>>>(msaF, W(10), W(11), lnb, 256);
    gemm_k<0,0,0><<<GEMM_GRID(32768,256),256,0,stream>>>(lnb, W(13),     bufA, nullptr, nullptr, 32768,256,256, 768, 0,0);
    gemm_k<0,0,0><<<GEMM_GRID(32768,256),256,0,stream>>>(lnb, W(13)+256, bufB, nullptr, nullptr, 32768,256,256, 768, 0,0);
    attn2_k<0,2,256><<<dim3(8,256),256,smem_col,stream>>>(bufA, bufB, lnb, W(13), nullptr, 8, 1, 256);
    gemm_k<0,0,0><<<GEMM_GRID(32768,256),256,0,stream>>>(lnb, W(12), bufB, nullptr, nullptr, 32768,256,256, 256, 0,0);
    mulsig_k<<<32768,256,0,stream>>>(bufA, bufB, MSA_N);
    gemm_k<0,0,1><<<GEMM_GRID(32768,256),256,0,stream>>>(bufA, W(14), nullptr, msaF, nullptr, 32768,256,256, 256, 0,0);

    // ================= MSA transition (FF chunked 4 x 256) =================
    ln_k<float><<<32768,256,0,stream>>>(msaF, W(15), W(16), lnb, 256);
    for (int ch=0; ch<4; ++ch){
        gemm_k<2,0,0><<<GEMM_GRID(32768,256),256,0,stream>>>(lnb, W(17)+ch*256, bufA, nullptr, nullptr, 32768,256,256, 1024, 0,0);
        gemm_k<0,0,1><<<GEMM_GRID(32768,256),256,0,stream>>>(bufA, W(18)+(size_t)ch*256*256, nullptr, msaF, nullptr, 32768,256,256, 256, 0,0);
    }

    // ================= Outer product mean (chunked 8 x 32 r's; chunks reuse lnb) =================
    ln_k<float><<<32768,256,0,stream>>>(msaF, W(19), W(20), lnb, 256);
    gemm_k<0,0,0><<<GEMM_GRID(32768,32),256,0,stream>>>(lnb, W(21), bufA, nullptr, nullptr, 32768,32,256, 32, 0,0);
    gemm_k<0,0,0><<<GEMM_GRID(32768,32),256,0,stream>>>(lnb, W(22), bufB, nullptr, nullptr, 32768,32,256, 32, 0,0);
    for (int ch=0; ch<8; ++ch){   // lnb (LN(msa)) dead now; reuse as 8192x1024 chunk buffer
        outer_k<<<dim3(256,32),256,0,stream>>>(bufA, bufB, lnb, ch*32);
        gemm_k<0,0,1><<<GEMM_GRID(8192,128),256,0,stream>>>(lnb, W(23), nullptr, pairF, nullptr, 8192,128,1024, 128, ch*8192,0);
    }

    // ================= Triangle mult outgoing / incoming =================
    for (int tm=0; tm<2; ++tm){
        int o = tm ? 34 : 24;   // tmi_* : tmo_*
        int inc = tm;
        ln_k<float><<<65536,128,0,stream>>>(pairF, W(o+0), W(o+1), lnb, 128);
        gemm_k<1,0,0><<<GEMM_GRID(65536,128),256,0,stream>>>(lnb, W(o+4), bufA, nullptr, nullptr, 65536,128,128, 128, 0,0); // sig(xn@p1)
        gemm_k<0,1,0><<<GEMM_GRID(65536,128),256,0,stream>>>(lnb, W(o+5), bufA, nullptr, bufA,   65536,128,128, 128, 0,0); // a
        gemm_k<1,0,0><<<GEMM_GRID(65536,128),256,0,stream>>>(lnb, W(o+6), bufB, nullptr, nullptr, 65536,128,128, 128, 0,0); // sig(xn@p3)
        gemm_k<0,1,0><<<GEMM_GRID(65536,128),256,0,stream>>>(lnb, W(o+7), bufB, nullptr, bufB,   65536,128,128, 128, 0,0); // b
        trimul_k<<<dim3(256,256),128,0,stream>>>(bufA, bufB, lnb, inc);       // p -> lnb (LN(pair) dead)
        ln_k<bf16><<<65536,128,0,stream>>>(lnb, W(o+2), W(o+3), bufA, 128);   // LN(p) -> bufA (a dead)
        ln_k<float><<<65536,128,0,stream>>>(pairF, W(o+0), W(o+1), lnb, 128); // re-LN pair -> lnb (p dead)
        gemm_k<1,0,0><<<GEMM_GRID(65536,128),256,0,stream>>>(lnb, W(o+9), bufB, nullptr, nullptr, 65536,128,128, 128, 0,0); // g (b dead)
        gemm_k<0,1,1><<<GEMM_GRID(65536,128),256,0,stream>>>(bufA, W(o+8), nullptr, pairF, bufB, 65536,128,128, 128, 0, inc);
    }

    // ================= Triangle attention starting (tas) =================
    ln_k<float><<<65536,128,0,stream>>>(pairF, W(44), W(45), lnb, 128);
    ln_bias_k<<<65536,128,0,stream>>>(pairF, W(44), W(45), W(49), biasF, 4, 1);
    gemm_k<0,0,0><<<GEMM_GRID(65536,128),256,0,stream>>>(lnb, W(47),     bufA, nullptr, nullptr, 65536,128,128, 384, 0,0);
    gemm_k<0,0,0><<<GEMM_GRID(65536,128),256,0,stream>>>(lnb, W(47)+128, bufB, nullptr, nullptr, 65536,128,128, 384, 0,0);
    attn2_k<2,4,128><<<dim3(4,256),256,smem_tri,stream>>>(bufA, bufB, lnb, W(47), biasF, 4, 256, 1);
    gemm_k<0,0,0><<<GEMM_GRID(65536,128),256,0,stream>>>(lnb, W(46), bufB, nullptr, nullptr, 65536,128,128, 128, 0,0);
    mulsig_k<<<32768,256,0,stream>>>(bufA, bufB, PAIR_N);
    gemm_k<0,0,1><<<GEMM_GRID(65536,128),256,0,stream>>>(bufA, W(48), nullptr, pairF, nullptr, 65536,128,128, 128, 0,0);

    // ================= Triangle attention ending (tae) =================
    ln_k<float><<<65536,128,0,stream>>>(pairF, W(50), W(51), lnb, 128);
    ln_bias_k<<<65536,128,0,stream>>>(pairF, W(50), W(51), W(55), biasF, 4, 2);
    gemm_k<0,0,0><<<GEMM_GRID(65536,128),256,0,stream>>>(lnb, W(53),     bufA, nullptr, nullptr, 65536,128,128, 384, 0,0);
    gemm_k<0,0,0><<<GEMM_GRID(65536,128),256,0,stream>>>(lnb, W(53)+128, bufB, nullptr, nullptr, 65536,128,128, 384, 0,0);
    attn2_k<2,4,128><<<dim3(4,256),256,smem_tri,stream>>>(bufA, bufB, lnb, W(53), biasF, 4, 1, 256);
    gemm_k<0,0,0><<<GEMM_GRID(65536,128),256,0,stream>>>(lnb, W(52), bufB, nullptr, nullptr, 65536,128,128, 128, 0,0);
    mulsig_k<<<32768,256,0,stream>>>(bufA, bufB, PAIR_N);
    gemm_k<0,0,1><<<GEMM_GRID(65536,128),256,0,stream>>>(bufA, W(54), nullptr, pairF, nullptr, 65536,128,128, 128, 0,0);

    // ================= Pair transition (FF chunked 4 x 128) =================
    ln_k<float><<<65536,128,0,stream>>>(pairF, W(56), W(57), lnb, 128);
    for (int ch=0; ch<4; ++ch){
        gemm_k<2,0,0><<<GEMM_GRID(65536,128),256,0,stream>>>(lnb, W(58)+ch*128, bufA, nullptr, nullptr, 65536,128,128, 512, 0,0);
        gemm_k<0,0,1><<<GEMM_GRID(65536,128),256,0,stream>>>(bufA, W(59)+(size_t)ch*128*128, nullptr, pairF, nullptr, 65536,128,128, 128, 0,0);
    }
    // outputs are msaF/pairF in d_out (f32) — done.
}

// Round 5
// 7822.799 us; speedup vs baseline: 1.6858x; 1.6858x over previous
//
#include <hip/hip_runtime.h>
#include <hip/hip_bf16.h>
#include <stdint.h>

typedef __hip_bfloat16 bf16;

// Shapes (N=1): S=128, R=256, CM=256, CZ=128, C=32, MSA_H=8, PAIR_H=4, CTM=128, FF=4
// msa rows: s*256+r (32768 x 256); pair rows: i*256+j (65536 x 128)
// I/O dtype: FLOAT32. Accumulators f32 live directly in d_out (they ARE the outputs).
// Workspace (70 MB): weights 4MB | biasF 2MB | lnb 16MB | bufA 16MB | bufB 16MB | bufC 16MB.

__device__ __forceinline__ float toF(float x){ return x; }
__device__ __forceinline__ float toF(bf16 x){ return __bfloat162float(x); }
__device__ __forceinline__ bf16  toB(float x){ return __float2bfloat16(x); }

// ---------------- input staging (dtype probe: bf16 ones -> 0x3F803F80, f32 one -> 0x3F800000) ----------------
__global__ void cvt_w_k(const void* __restrict__ in, bf16* __restrict__ out, int n,
                        const uint32_t* __restrict__ probe){
    bool isbf = (probe[0] == 0x3F803F80u);
    int i = blockIdx.x*256 + threadIdx.x;
    if (i < n) out[i] = isbf ? ((const bf16*)in)[i] : toB(((const float*)in)[i]);
}
__global__ void in2f_k(const void* __restrict__ in, float* __restrict__ out, int n,
                       const uint32_t* __restrict__ probe){
    bool isbf = (probe[0] == 0x3F803F80u);
    int i = blockIdx.x*256 + threadIdx.x;
    if (i < n) out[i] = isbf ? toF(((const bf16*)in)[i]) : ((const float*)in)[i];
}

// ---------------- LayerNorm: one block per row, blockDim = D (128 or 256); in-place safe ----------------
template<typename T>
__global__ void ln_k(const T* __restrict__ x, const bf16* __restrict__ w, const bf16* __restrict__ b,
                     bf16* __restrict__ out, int D){
    int row = blockIdx.x, c = threadIdx.x;
    float v = toF(x[(size_t)row*D + c]);
    float s1 = v, s2 = v*v;
    #pragma unroll
    for (int o=32;o>0;o>>=1){ s1 += __shfl_down(s1,o); s2 += __shfl_down(s2,o); }
    __shared__ float r1[4], r2[4];
    int lane = c & 63, wid = c >> 6;
    if (lane==0){ r1[wid]=s1; r2[wid]=s2; }
    __syncthreads();
    int nw = blockDim.x >> 6;
    float m=0.f, q=0.f;
    for (int i=0;i<nw;i++){ m+=r1[i]; q+=r2[i]; }
    m /= (float)D; q = q/(float)D - m*m;
    float inv = rsqrtf(q + 1e-5f);
    out[(size_t)row*D + c] = toB((v-m)*inv*toF(w[c]) + toF(b[c]));
}

// ---------------- fused LN + attention-bias projection (reads f32 pair acc) ----------------
// mode 0 (row attn, Hn=8): out[(h*256+j)*256+i]  ([h][k][q] layout -> lane-coalesced reads)
// mode 1 (tas, Hn=4):      out[(i*Hn+h)*256+j]
// mode 2 (tae, Hn=4):      out[(j*Hn+h)*256+i].  Value = dot(LN(pair[i,j]), Wb[:,h]).
__global__ void ln_bias_k(const float* __restrict__ pairf, const bf16* __restrict__ w, const bf16* __restrict__ b,
                          const bf16* __restrict__ Wb, float* __restrict__ outb, int Hn, int mode){
    int pp = blockIdx.x, c = threadIdx.x;           // 128 threads
    int i = pp >> 8, j = pp & 255;
    float v = pairf[(size_t)pp*128 + c];
    float s1 = v, s2 = v*v;
    #pragma unroll
    for (int o=32;o>0;o>>=1){ s1 += __shfl_down(s1,o); s2 += __shfl_down(s2,o); }
    __shared__ float r1[2], r2[2], rh[2];
    int lane = c & 63, wid = c >> 6;
    if (lane==0){ r1[wid]=s1; r2[wid]=s2; }
    __syncthreads();
    float m = (r1[0]+r1[1])*(1.f/128.f);
    float q = (r2[0]+r2[1])*(1.f/128.f) - m*m;
    float xn = (v-m)*rsqrtf(q+1e-5f)*toF(w[c]) + toF(b[c]);
    for (int h=0; h<Hn; ++h){
        float p = xn*toF(Wb[c*Hn + h]);
        #pragma unroll
        for (int o=32;o>0;o>>=1) p += __shfl_down(p,o);
        if (lane==0) rh[wid]=p;
        __syncthreads();
        if (c==0){
            float sv = rh[0]+rh[1];
            size_t idx = (mode==0) ? ((size_t)(h*256+j)*256 + i)
                       : (mode==1) ? ((size_t)(i*Hn+h)*256 + j)
                                   : ((size_t)(j*Hn+h)*256 + i);
            outb[idx] = sv;
        }
        __syncthreads();
    }
}

// ---------------- generic tiled GEMM (bf16 in, fp32 math), B row-stride ldb ----------------
// ACT: 0 none, 1 sigmoid, 2 relu. MUL: x *= Mul[m (or transposed)]. RES: f32 Res[m+res_off] += x, else C=bf16.
template<int ACT, int MUL, int RES>
__global__ __launch_bounds__(256) void gemm_k(const bf16* __restrict__ A, const bf16* __restrict__ Bw,
                                              bf16* __restrict__ C, float* __restrict__ Res,
                                              const bf16* __restrict__ Mul,
                                              int M, int N, int K, int ldb, int res_off, int gtrans){
    __shared__ float As[64][33];
    __shared__ float Bs[32][65];
    int tid = threadIdx.x;
    int m0 = blockIdx.y*64, n0 = blockIdx.x*64;
    int tx = tid & 15, ty = tid >> 4;
    float acc[4][4] = {};
    for (int k0=0; k0<K; k0+=32){
        for (int i=tid; i<64*32; i+=256){
            int r = i>>5, cc = i&31;
            As[r][cc] = toF(A[(size_t)(m0+r)*K + k0 + cc]);
        }
        for (int i=tid; i<32*64; i+=256){
            int r = i>>6, cc = i&63; int col = n0+cc;
            Bs[r][cc] = (col < N) ? toF(Bw[(size_t)(k0+r)*ldb + col]) : 0.f;
        }
        __syncthreads();
        #pragma unroll 8
        for (int k=0;k<32;k++){
            float a4[4], b4[4];
            #pragma unroll
            for (int i=0;i<4;i++) a4[i] = As[ty*4+i][k];
            #pragma unroll
            for (int j=0;j<4;j++) b4[j] = Bs[k][tx*4+j];
            #pragma unroll
            for (int i=0;i<4;i++)
                #pragma unroll
                for (int j=0;j<4;j++) acc[i][j] += a4[i]*b4[j];
        }
        __syncthreads();
    }
    #pragma unroll
    for (int i=0;i<4;i++){
        int m = m0 + ty*4 + i;
        #pragma unroll
        for (int j=0;j<4;j++){
            int n = n0 + tx*4 + j;
            if (n >= N) continue;
            float x = acc[i][j];
            if (ACT==1) x = 1.f/(1.f + __expf(-x));
            else if (ACT==2) x = fmaxf(x, 0.f);
            if (MUL){
                int mr = gtrans ? (((m & 255) << 8) | (m >> 8)) : m;
                x *= toF(Mul[(size_t)mr*N + n]);
            }
            if (RES) Res[(size_t)(m + res_off)*N + n] += x;
            else     C[(size_t)m*N + n] = toB(x);
        }
    }
}

// ---------------- attention v3: lane-per-query, register flash softmax ----------------
// Grid (H, O); block NW*64 threads; lane tid owns query q=tid (L == NW*64).
// pos(l) = o*sO + l*sL; row stride GN=H*32. QO: Q in / ungated attn out (in place,
// block-disjoint slices). K/V staged to LDS f32 (k-loop reads are wave-uniform broadcasts).
// Per-lane softmax without max-subtraction (scores LN-bounded, |s| << 80).
// BIAS: 0 none; 1 row attn, layout [h][k][q]: bias[(h*256+k)*256+q] (coalesced);
//       2 tri attn, layout [(o*H+h)][k] (wave-uniform). Bias added POST-softmax: O = Os/l + (bias@V).
template<int BIAS, int L, int NW>
__global__ __launch_bounds__(NW*64) void attn3_k(bf16* __restrict__ QO,
                                                 const bf16* __restrict__ Kp, const bf16* __restrict__ Vp,
                                                 const float* __restrict__ bias,
                                                 int H, int sO, int sL){
    __shared__ float Kt[L*32];
    __shared__ float Vt[L*32];
    const int o = blockIdx.y, h = blockIdx.x, tid = threadIdx.x;
    const int GN = H*32;
    for (int idx=tid; idx<L*16; idx+=NW*64){      // 2 bf16 per iteration
        int l = idx >> 4, c2 = (idx & 15)*2;
        size_t p = (size_t)(o*sO + l*sL)*GN + h*32 + c2;
        uint32_t kk = *(const uint32_t*)(Kp + p);
        uint32_t vv = *(const uint32_t*)(Vp + p);
        Kt[l*32 + c2]   = __uint_as_float(kk << 16);
        Kt[l*32 + c2+1] = __uint_as_float(kk & 0xFFFF0000u);
        Vt[l*32 + c2]   = __uint_as_float(vv << 16);
        Vt[l*32 + c2+1] = __uint_as_float(vv & 0xFFFF0000u);
    }
    __syncthreads();
    const int q = tid;
    size_t pq = (size_t)(o*sO + q*sL)*GN + h*32;
    float qv[32];
    {   const uint4* qp = (const uint4*)(QO + pq);   // 64B aligned
        #pragma unroll
        for (int i=0;i<4;i++){
            uint4 r = qp[i];
            uint32_t u0=r.x,u1=r.y,u2=r.z,u3=r.w;
            qv[i*8+0]=__uint_as_float(u0<<16); qv[i*8+1]=__uint_as_float(u0&0xFFFF0000u);
            qv[i*8+2]=__uint_as_float(u1<<16); qv[i*8+3]=__uint_as_float(u1&0xFFFF0000u);
            qv[i*8+4]=__uint_as_float(u2<<16); qv[i*8+5]=__uint_as_float(u2&0xFFFF0000u);
            qv[i*8+6]=__uint_as_float(u3<<16); qv[i*8+7]=__uint_as_float(u3&0xFFFF0000u);
        }
    }
    float Os[32], Ob[32];
    #pragma unroll
    for (int c=0;c<32;c++){ Os[c]=0.f; Ob[c]=0.f; }
    float lsum = 0.f;
    const float* bp = (BIAS==1) ? (bias + (size_t)h*65536 + q)
                    : (BIAS==2) ? (bias + ((size_t)(o*H+h))*256) : (const float*)nullptr;
    for (int k=0;k<L;k++){
        float s = 0.f;
        #pragma unroll
        for (int c=0;c<32;c++) s += qv[c]*Kt[k*32+c];
        float e = __expf(s * 0.17677669529663687f);   // 1/sqrt(32) folded into exp arg
        lsum += e;
        #pragma unroll
        for (int c=0;c<32;c++) Os[c] += e*Vt[k*32+c];
        if (BIAS){
            float bv = (BIAS==1) ? bp[(size_t)k*256] : bp[k];
            #pragma unroll
            for (int c=0;c<32;c++) Ob[c] += bv*Vt[k*32+c];
        }
    }
    float inv = 1.f/lsum;
    #pragma unroll
    for (int c=0;c<32;c++)
        QO[pq + c] = toB(Os[c]*inv + (BIAS ? Ob[c] : 0.f));
}

// ---------------- elementwise: a *= sigmoid(g) ----------------
__global__ void mulsig_k(bf16* __restrict__ a, const bf16* __restrict__ g, int n){
    int i = blockIdx.x*256 + threadIdx.x;
    if (i < n){
        float sg = 1.f/(1.f + __expf(-toF(g[i])));
        a[i] = toB(toF(a[i]) * sg);
    }
}

// ---------------- triangle multiplication einsum ----------------
// outgoing: p[s,t,k] = sum_r a[s,r,k]*b[t,r,k]; incoming: p[s,t,k] = sum_r a[r,s,k]*b[r,t,k]
__global__ void trimul_k(const bf16* __restrict__ a, const bf16* __restrict__ b, bf16* __restrict__ p, int incoming){
    int t = blockIdx.x, s = blockIdx.y, k = threadIdx.x;   // 128 threads
    float acc = 0.f;
    if (!incoming){
        const bf16* pa = a + (size_t)(s*256)*128 + k;
        const bf16* pb = b + (size_t)(t*256)*128 + k;
        for (int r=0;r<256;r++) acc += toF(pa[(size_t)r*128]) * toF(pb[(size_t)r*128]);
    } else {
        const bf16* pa = a + (size_t)s*128 + k;
        const bf16* pb = b + (size_t)t*128 + k;
        for (int r=0;r<256;r++) acc += toF(pa[(size_t)r*32768]) * toF(pb[(size_t)r*32768]);
    }
    p[((size_t)s*256 + t)*128 + k] = toB(acc);
}

// ---------------- outer product einsum, chunked over r (32 r's per chunk) ----------------
__global__ __launch_bounds__(256) void outer_k(const bf16* __restrict__ ap, const bf16* __restrict__ bp,
                                               bf16* __restrict__ outc, int r0){
    int t = blockIdx.x, rl = blockIdx.y, r = r0 + rl;
    __shared__ float As[128*32], Bs[128*32];
    for (int idx=threadIdx.x; idx<128*32; idx+=256){
        int s = idx>>5, c = idx&31;
        As[idx] = toF(ap[((size_t)s*256 + r)*32 + c]);
        Bs[idx] = toF(bp[((size_t)s*256 + t)*32 + c]);
    }
    __syncthreads();
    int ce0 = threadIdx.x*4;
    int c = ce0 >> 5, e0 = ce0 & 31;
    float acc[4] = {0.f,0.f,0.f,0.f};
    for (int s=0;s<128;s++){
        float av = As[s*32 + c];
        #pragma unroll
        for (int j=0;j<4;j++) acc[j] += av*Bs[s*32 + e0 + j];
    }
    size_t row = (size_t)rl*256 + t;
    #pragma unroll
    for (int j=0;j<4;j++) outc[row*1024 + ce0 + j] = toB(acc[j]);
}

// ================= host =================
extern "C" void kernel_launch(void* const* d_in, const int* in_sizes, int n_in,
                              void* d_out, int out_size, void* d_ws, size_t ws_size,
                              hipStream_t stream){
    (void)n_in; (void)out_size; (void)ws_size;
    const int MSA_N  = 128*256*256;   // 8388608
    const int PAIR_N = 256*256*128;   // 8388608
    const uint32_t* probe = (const uint32_t*)d_in[2];   // row_norm_m_w = ones

    // ---- workspace layout: 70 MB ----
    char*  w     = (char*)d_ws;
    bf16*  wsts  = (bf16*)(w);                 // [0, 4MB) staged bf16 weights
    float* biasF = (float*)(w + 4194304);      // [4MB, 6MB)
    bf16*  lnb   = (bf16*)(w + 6291456);       // [6MB, 22MB)
    bf16*  bufA  = (bf16*)(w + 23068672);      // [22MB, 38MB)
    bf16*  bufB  = (bf16*)(w + 39845888);      // [38MB, 54MB)
    bf16*  bufC  = (bf16*)(w + 56623104);      // [54MB, 70MB)

    float* msaF  = (float*)d_out;              // f32 msa accumulator == output 0
    float* pairF = msaF + MSA_N;               // f32 pair accumulator == output 1

    // ---- stage all weights (inputs 2..59) to bf16 ----
    size_t woff[64]; { size_t acc = 0;
        for (int i=2;i<60;i++){ woff[i] = acc; acc += ((size_t)in_sizes[i] + 63) & ~(size_t)63; } }
    #define W(i) (wsts + woff[i])
    for (int i=2;i<60;i++)
        cvt_w_k<<<(in_sizes[i]+255)/256,256,0,stream>>>(d_in[i], W(i), in_sizes[i], probe);

    in2f_k<<<32768,256,0,stream>>>(d_in[0], msaF,  MSA_N,  probe);
    in2f_k<<<32768,256,0,stream>>>(d_in[1], pairF, PAIR_N, probe);

    #define GEMM_GRID(M,N) dim3(((N)+63)/64, (M)/64)

    // ================= Row attention (bias = LN(pair)@row_bias, post-softmax) =================
    ln_k<float><<<32768,256,0,stream>>>(msaF, W(2), W(3), lnb, 256);
    ln_bias_k<<<65536,128,0,stream>>>(pairF, W(4), W(5), W(9), biasF, 8, 0);
    gemm_k<0,0,0><<<GEMM_GRID(32768,256),256,0,stream>>>(lnb, W(7),     bufA, nullptr, nullptr, 32768,256,256, 768, 0,0); // Q
    gemm_k<0,0,0><<<GEMM_GRID(32768,256),256,0,stream>>>(lnb, W(7)+256, bufB, nullptr, nullptr, 32768,256,256, 768, 0,0); // K
    gemm_k<0,0,0><<<GEMM_GRID(32768,256),256,0,stream>>>(lnb, W(7)+512, bufC, nullptr, nullptr, 32768,256,256, 768, 0,0); // V
    attn3_k<1,256,4><<<dim3(8,128),256,0,stream>>>(bufA, bufB, bufC, biasF, 8, 256, 1);
    gemm_k<0,0,0><<<GEMM_GRID(32768,256),256,0,stream>>>(lnb, W(6), bufB, nullptr, nullptr, 32768,256,256, 256, 0,0);     // gate raw
    mulsig_k<<<32768,256,0,stream>>>(bufA, bufB, MSA_N);
    gemm_k<0,0,1><<<GEMM_GRID(32768,256),256,0,stream>>>(bufA, W(8), nullptr, msaF, nullptr, 32768,256,256, 256, 0,0);

    // ================= Column attention (attend over s, L=128, no bias) =================
    ln_k<float><<<32768,256,0,stream>>>(msaF, W(10), W(11), lnb, 256);
    gemm_k<0,0,0><<<GEMM_GRID(32768,256),256,0,stream>>>(lnb, W(13),     bufA, nullptr, nullptr, 32768,256,256, 768, 0,0);
    gemm_k<0,0,0><<<GEMM_GRID(32768,256),256,0,stream>>>(lnb, W(13)+256, bufB, nullptr, nullptr, 32768,256,256, 768, 0,0);
    gemm_k<0,0,0><<<GEMM_GRID(32768,256),256,0,stream>>>(lnb, W(13)+512, bufC, nullptr, nullptr, 32768,256,256, 768, 0,0);
    attn3_k<0,128,2><<<dim3(8,256),128,0,stream>>>(bufA, bufB, bufC, nullptr, 8, 1, 256);
    gemm_k<0,0,0><<<GEMM_GRID(32768,256),256,0,stream>>>(lnb, W(12), bufB, nullptr, nullptr, 32768,256,256, 256, 0,0);
    mulsig_k<<<32768,256,0,stream>>>(bufA, bufB, MSA_N);
    gemm_k<0,0,1><<<GEMM_GRID(32768,256),256,0,stream>>>(bufA, W(14), nullptr, msaF, nullptr, 32768,256,256, 256, 0,0);

    // ================= MSA transition (FF chunked 4 x 256) =================
    ln_k<float><<<32768,256,0,stream>>>(msaF, W(15), W(16), lnb, 256);
    for (int ch=0; ch<4; ++ch){
        gemm_k<2,0,0><<<GEMM_GRID(32768,256),256,0,stream>>>(lnb, W(17)+ch*256, bufA, nullptr, nullptr, 32768,256,256, 1024, 0,0);
        gemm_k<0,0,1><<<GEMM_GRID(32768,256),256,0,stream>>>(bufA, W(18)+(size_t)ch*256*256, nullptr, msaF, nullptr, 32768,256,256, 256, 0,0);
    }

    // ================= Outer product mean (chunked 8 x 32 r's; chunks reuse lnb) =================
    ln_k<float><<<32768,256,0,stream>>>(msaF, W(19), W(20), lnb, 256);
    gemm_k<0,0,0><<<GEMM_GRID(32768,32),256,0,stream>>>(lnb, W(21), bufA, nullptr, nullptr, 32768,32,256, 32, 0,0);
    gemm_k<0,0,0><<<GEMM_GRID(32768,32),256,0,stream>>>(lnb, W(22), bufB, nullptr, nullptr, 32768,32,256, 32, 0,0);
    for (int ch=0; ch<8; ++ch){   // lnb dead; reuse as 8192x1024 chunk buffer
        outer_k<<<dim3(256,32),256,0,stream>>>(bufA, bufB, lnb, ch*32);
        gemm_k<0,0,1><<<GEMM_GRID(8192,128),256,0,stream>>>(lnb, W(23), nullptr, pairF, nullptr, 8192,128,1024, 128, ch*8192,0);
    }

    // ================= Triangle mult outgoing / incoming =================
    for (int tm=0; tm<2; ++tm){
        int o = tm ? 34 : 24;   // tmi_* : tmo_*
        int inc = tm;
        ln_k<float><<<65536,128,0,stream>>>(pairF, W(o+0), W(o+1), lnb, 128);
        gemm_k<1,0,0><<<GEMM_GRID(65536,128),256,0,stream>>>(lnb, W(o+4), bufA, nullptr, nullptr, 65536,128,128, 128, 0,0); // sig(xn@p1)
        gemm_k<0,1,0><<<GEMM_GRID(65536,128),256,0,stream>>>(lnb, W(o+5), bufA, nullptr, bufA,   65536,128,128, 128, 0,0); // a
        gemm_k<1,0,0><<<GEMM_GRID(65536,128),256,0,stream>>>(lnb, W(o+6), bufB, nullptr, nullptr, 65536,128,128, 128, 0,0); // sig(xn@p3)
        gemm_k<0,1,0><<<GEMM_GRID(65536,128),256,0,stream>>>(lnb, W(o+7), bufB, nullptr, bufB,   65536,128,128, 128, 0,0); // b
        trimul_k<<<dim3(256,256),128,0,stream>>>(bufA, bufB, bufC, inc);      // p -> bufC
        ln_k<bf16><<<65536,128,0,stream>>>(bufC, W(o+2), W(o+3), bufC, 128);  // LN(p) in place
        gemm_k<1,0,0><<<GEMM_GRID(65536,128),256,0,stream>>>(lnb, W(o+9), bufA, nullptr, nullptr, 65536,128,128, 128, 0,0); // g (lnb intact)
        gemm_k<0,1,1><<<GEMM_GRID(65536,128),256,0,stream>>>(bufC, W(o+8), nullptr, pairF, bufA, 65536,128,128, 128, 0, inc);
    }

    // ================= Triangle attention starting (tas) =================
    ln_k<float><<<65536,128,0,stream>>>(pairF, W(44), W(45), lnb, 128);
    ln_bias_k<<<65536,128,0,stream>>>(pairF, W(44), W(45), W(49), biasF, 4, 1);
    gemm_k<0,0,0><<<GEMM_GRID(65536,128),256,0,stream>>>(lnb, W(47),     bufA, nullptr, nullptr, 65536,128,128, 384, 0,0);
    gemm_k<0,0,0><<<GEMM_GRID(65536,128),256,0,stream>>>(lnb, W(47)+128, bufB, nullptr, nullptr, 65536,128,128, 384, 0,0);
    gemm_k<0,0,0><<<GEMM_GRID(65536,128),256,0,stream>>>(lnb, W(47)+256, bufC, nullptr, nullptr, 65536,128,128, 384, 0,0);
    attn3_k<2,256,4><<<dim3(4,256),256,0,stream>>>(bufA, bufB, bufC, biasF, 4, 256, 1);
    gemm_k<0,0,0><<<GEMM_GRID(65536,128),256,0,stream>>>(lnb, W(46), bufB, nullptr, nullptr, 65536,128,128, 128, 0,0);
    mulsig_k<<<32768,256,0,stream>>>(bufA, bufB, PAIR_N);
    gemm_k<0,0,1><<<GEMM_GRID(65536,128),256,0,stream>>>(bufA, W(48), nullptr, pairF, nullptr, 65536,128,128, 128, 0,0);

    // ================= Triangle attention ending (tae) =================
    ln_k<float><<<65536,128,0,stream>>>(pairF, W(50), W(51), lnb, 128);
    ln_bias_k<<<65536,128,0,stream>>>(pairF, W(50), W(51), W(55), biasF, 4, 2);
    gemm_k<0,0,0><<<GEMM_GRID(65536,128),256,0,stream>>>(lnb, W(53),     bufA, nullptr, nullptr, 65536,128,128, 384, 0,0);
    gemm_k<0,0,0><<<GEMM_GRID(65536,128),256,0,stream>>>(lnb, W(53)+128, bufB, nullptr, nullptr, 65536,128,128, 384, 0,0);
    gemm_k<0,0,0><<<GEMM_GRID(65536,128),256,0,stream>>>(lnb, W(53)+256, bufC, nullptr, nullptr, 65536,128,128, 384, 0,0);
    attn3_k<2,256,4><<<dim3(4,256),256,0,stream>>>(bufA, bufB, bufC, biasF, 4, 1, 256);
    gemm_k<0,0,0><<<GEMM_GRID(65536,128),256,0,stream>>>(lnb, W(52), bufB, nullptr, nullptr, 65536,128,128, 128, 0,0);
    mulsig_k<<<32768,256,0,stream>>>(bufA, bufB, PAIR_N);
    gemm_k<0,0,1><<<GEMM_GRID(65536,128),256,0,stream>>>(bufA, W(54), nullptr, pairF, nullptr, 65536,128,128, 128, 0,0);

    // ================= Pair transition (FF chunked 4 x 128) =================
    ln_k<float><<<65536,128,0,stream>>>(pairF, W(56), W(57), lnb, 128);
    for (int ch=0; ch<4; ++ch){
        gemm_k<2,0,0><<<GEMM_GRID(65536,128),256,0,stream>>>(lnb, W(58)+ch*128, bufA, nullptr, nullptr, 65536,128,128, 512, 0,0);
        gemm_k<0,0,1><<<GEMM_GRID(65536,128),256,0,stream>>>(bufA, W(59)+(size_t)ch*128*128, nullptr, pairF, nullptr, 65536,128,128, 128, 0,0);
    }
    // outputs are msaF/pairF in d_out (f32) — done.
}